// Round 7
// baseline (527.828 us; speedup 1.0000x reference)
//
#include <hip/hip_runtime.h>
#include <hip/hip_bf16.h>
#include <cmath>

typedef float f32x4 __attribute__((ext_vector_type(4)));
typedef __bf16 bf16x8 __attribute__((ext_vector_type(8)));
typedef __bf16 bf16x4 __attribute__((ext_vector_type(4)));

#define WS_SZ 7
#define SHIFT 3
#define HGRID 56
#define C_DIM 192
#define NHEADS 6
#define HDIM 32
#define NTOK 100352   // 32 * 3136
#define NWIN 2048     // 32 * 8 * 8

// map window-space row (w*49+i) -> original token index (inverse roll by +SHIFT)
__device__ __forceinline__ int win_to_tok(int wrow) {
    int w = wrow / 49, i = wrow - w * 49;
    int b = w >> 6, rem = w & 63;
    int wy = rem >> 3, wx = rem & 7;
    int yi = i / 7, xi = i - yi * 7;
    int y = wy * 7 + yi + SHIFT; if (y >= HGRID) y -= HGRID;
    int x = wx * 7 + xi + SHIFT; if (x >= HGRID) x -= HGRID;
    return b * (HGRID * HGRID) + y * HGRID + x;
}

// ---------------- fp32 -> bf16 weight conversion (8 elems/thread) ----------------
__global__ __launch_bounds__(256)
void cvt_kernel(const float* __restrict__ src, __bf16* __restrict__ dst, int n8)
{
    int idx = blockIdx.x * 256 + threadIdx.x;
    if (idx >= n8) return;
    float4 a = ((const float4*)src)[idx * 2];
    float4 b = ((const float4*)src)[idx * 2 + 1];
    bf16x8 o;
    o[0] = (__bf16)a.x; o[1] = (__bf16)a.y; o[2] = (__bf16)a.z; o[3] = (__bf16)a.w;
    o[4] = (__bf16)b.x; o[5] = (__bf16)b.y; o[6] = (__bf16)b.z; o[7] = (__bf16)b.w;
    ((bf16x8*)dst)[idx] = o;
}

// ---------------- expand rel-pos bias -> bias_g[head][49][49] fp32 ----------------
__global__ __launch_bounds__(256)
void bias_expand_kernel(const float* __restrict__ rpb, float* __restrict__ bias_g)
{
    int idx = blockIdx.x * 256 + threadIdx.x;
    if (idx >= NHEADS * 2401) return;
    int h = idx / 2401, rem = idx - h * 2401;
    int i = rem / 49, j = rem - i * 49;
    int yi = i / 7, xi = i - yi * 7;
    int yj = j / 7, xj = j - yj * 7;
    int ri = (yi - yj + 6) * 13 + (xi - xj + 6);
    bias_g[idx] = rpb[ri * NHEADS + h];
}

// ---------------- Fused LN1 + QKV GEMM, zero barriers -----------------------------
// Block = 128 window-space rows, 4 waves; wave wn owns rows [wn*32,+32) end-to-end:
// LN1 (win_to_tok gather) -> wave-private LDS slice -> A frags hoisted to regs
// (af[6][2], 48 VGPR) -> 36 n-tiles of 16 cols, W frags double-buffered from L2.
// No __syncthreads anywhere (LDS slice is wave-private, DS in-order per wave).
__global__ __launch_bounds__(256, 3)
void qkv_ln_kernel(const float* __restrict__ x, const float* __restrict__ n1w,
                   const float* __restrict__ n1b,
                   const __bf16* __restrict__ qw,   // 576 x 192 bf16
                   const float* __restrict__ qb,    // 576
                   __bf16* __restrict__ outq)       // NTOK x 576 bf16 (window space)
{
    __shared__ __bf16 As[128 * 200];   // 51.2KB -> 3 blocks/CU
    const int tid = threadIdx.x;
    const int wn = tid >> 6, lane = tid & 63;
    const int l15 = lane & 15, q4 = lane >> 4, q8 = q4 << 3;
    const int m0 = blockIdx.x * 128;
    const int r0 = wn * 32;
    __bf16* As_w = &As[r0 * 200];

    // prefetch W frags + bias for tn=0 (in flight across the whole LN phase)
    bf16x8 wf[2][6];
    #pragma unroll
    for (int kt = 0; kt < 6; ++kt)
        wf[0][kt] = *(const bf16x8*)(qw + (size_t)l15 * 192 + kt * 32 + q8);
    float bvf[2];
    bvf[0] = qb[l15];

    // ---- LN1 on own 32 rows (gathered via win_to_tok) -> wave-private LDS ----
    {
        const float wl0 = n1w[lane], wl1 = n1w[lane + 64], wl2 = n1w[lane + 128];
        const float bl0 = n1b[lane], bl1 = n1b[lane + 64], bl2 = n1b[lane + 128];
        #pragma unroll 4
        for (int rr = 0; rr < 32; ++rr) {
            const float* xp = x + (size_t)win_to_tok(m0 + r0 + rr) * C_DIM;
            float v0 = xp[lane], v1 = xp[lane + 64], v2 = xp[lane + 128];
            float s = v0 + v1 + v2;
            float sq = v0 * v0 + v1 * v1 + v2 * v2;
            #pragma unroll
            for (int off = 32; off; off >>= 1) {
                s  += __shfl_xor(s, off);
                sq += __shfl_xor(sq, off);
            }
            float mu = s * (1.f / C_DIM);
            float rs = rsqrtf(sq * (1.f / C_DIM) - mu * mu + 1e-5f);
            As_w[rr * 200 + lane]       = (__bf16)((v0 - mu) * rs * wl0 + bl0);
            As_w[rr * 200 + lane + 64]  = (__bf16)((v1 - mu) * rs * wl1 + bl1);
            As_w[rr * 200 + lane + 128] = (__bf16)((v2 - mu) * rs * wl2 + bl2);
        }
    }
    // no barrier: wave reads only its own slice

    // ---- hoist A tile (32x192 per wave) into registers ----
    bf16x8 af[6][2];
    #pragma unroll
    for (int kt = 0; kt < 6; ++kt)
        #pragma unroll
        for (int tm = 0; tm < 2; ++tm)
            af[kt][tm] = *(const bf16x8*)(&As_w[(tm * 16 + l15) * 200 + kt * 32 + q8]);

    f32x4 zero = {0.f, 0.f, 0.f, 0.f};

    // ---- 36 n-tiles of 16 cols; W frags double-buffered ----
    #pragma unroll 4
    for (int tn = 0; tn < 36; ++tn) {
        const int cur = tn & 1, nxt = cur ^ 1;
        if (tn < 35) {
            #pragma unroll
            for (int kt = 0; kt < 6; ++kt)
                wf[nxt][kt] = *(const bf16x8*)(qw + (size_t)((tn + 1) * 16 + l15) * 192 + kt * 32 + q8);
            bvf[nxt] = qb[(tn + 1) * 16 + l15];
        }
        f32x4 acc[2];
        acc[0] = zero; acc[1] = zero;
        __builtin_amdgcn_s_setprio(1);
        #pragma unroll
        for (int kt = 0; kt < 6; ++kt)
            #pragma unroll
            for (int tm = 0; tm < 2; ++tm)
                acc[tm] = __builtin_amdgcn_mfma_f32_16x16x32_bf16(
                    af[kt][tm], wf[cur][kt], acc[tm], 0, 0, 0);
        __builtin_amdgcn_s_setprio(0);
        const float bv = bvf[cur];
        const int c = tn * 16 + l15;
        #pragma unroll
        for (int tm = 0; tm < 2; ++tm)
            #pragma unroll
            for (int r = 0; r < 4; ++r) {
                int m = m0 + r0 + tm * 16 + q4 * 4 + r;
                outq[(size_t)m * 576 + c] = (__bf16)(acc[tm][r] + bv);
            }
    }
}

// ---------------- GEMM: out = A(bf16, MxK) @ W(bf16, NxK)^T + bias ----------------
// MODE 1: window-reverse scatter + residual -> fp32. (MODE 0 retired.)
template<int MODE>
__global__ __launch_bounds__(256)
void gemm_kernel(const __bf16* __restrict__ A, const __bf16* __restrict__ W,
                 const float* __restrict__ bias, void* __restrict__ outp,
                 const float* __restrict__ resid, int N, int K)
{
    __shared__ __bf16 As[128 * 40];
    __shared__ __bf16 Bs[64 * 40];
    const int tid = threadIdx.x;
    const int wave = tid >> 6, lane = tid & 63;
    const int wm = wave >> 1, wn = wave & 1;
    const int l15 = lane & 15, q8 = (lane >> 4) << 3;
    const int m0 = blockIdx.y * 128, n0 = blockIdx.x * 64;

    f32x4 acc[4][2];
    f32x4 zero = {0.f, 0.f, 0.f, 0.f};
    #pragma unroll
    for (int i = 0; i < 4; i++)
        #pragma unroll
        for (int j = 0; j < 2; j++) acc[i][j] = zero;

    const int br = tid >> 2, bc = (tid & 3) << 3;
    for (int kt = 0; kt < K; kt += 32) {
        __syncthreads();
        #pragma unroll
        for (int it = 0; it < 2; it++) {
            int idx = it * 256 + tid;
            int r = idx >> 2, c = (idx & 3) << 3;
            *(uint4*)(&As[r * 40 + c]) =
                *(const uint4*)(A + (size_t)(m0 + r) * K + kt + c);
        }
        *(uint4*)(&Bs[br * 40 + bc]) =
            *(const uint4*)(W + (size_t)(n0 + br) * K + kt + bc);
        __syncthreads();
        bf16x8 af[4], bfr[2];
        #pragma unroll
        for (int fm = 0; fm < 4; fm++)
            af[fm] = *(const bf16x8*)(&As[(wm * 64 + fm * 16 + l15) * 40 + q8]);
        #pragma unroll
        for (int fn = 0; fn < 2; fn++)
            bfr[fn] = *(const bf16x8*)(&Bs[(wn * 32 + fn * 16 + l15) * 40 + q8]);
        #pragma unroll
        for (int fm = 0; fm < 4; fm++)
            #pragma unroll
            for (int fn = 0; fn < 2; fn++)
                acc[fm][fn] = __builtin_amdgcn_mfma_f32_16x16x32_bf16(
                    af[fm], bfr[fn], acc[fm][fn], 0, 0, 0);
    }

    const int l4 = lane >> 4;
    #pragma unroll
    for (int fm = 0; fm < 4; fm++) {
        #pragma unroll
        for (int fn = 0; fn < 2; fn++) {
            int c = n0 + wn * 32 + fn * 16 + l15;
            float bv = bias[c];
            #pragma unroll
            for (int r = 0; r < 4; r++) {
                int m = m0 + wm * 64 + fm * 16 + l4 * 4 + r;
                float v = acc[fm][fn][r] + bv;
                if (MODE == 0) {
                    ((__bf16*)outp)[(size_t)m * N + c] = (__bf16)v;
                } else {
                    int t = win_to_tok(m);
                    ((float*)outp)[(size_t)t * C_DIM + c] =
                        resid[(size_t)t * C_DIM + c] + v;
                }
            }
        }
    }
}

// ---------------- Fused LN2 + MLP (exact R4 structure, best measured: 159us) ----
__global__ __launch_bounds__(256, 3)
void mlp_fused_kernel(const float* __restrict__ n2w, const float* __restrict__ n2b,
                      const __bf16* __restrict__ w1,  // 768 x 192
                      const float* __restrict__ b1,
                      const __bf16* __restrict__ w2,  // 192 x 768
                      const float* __restrict__ b2,
                      float* __restrict__ out)        // NTOK x 192 fp32, RMW
{
    __shared__ __align__(16) __bf16 As[64 * 200]; // 25600B; reused as fp32 Cs[32][196]
    __shared__ __bf16 Hs[64 * 72];                // 9216B, stride 144B: 2-way banks
    const int tid = threadIdx.x;
    const int wn = tid >> 6, lane = tid & 63;
    const int l15 = lane & 15, q4 = lane >> 4, q8 = q4 << 3;
    const int m0 = blockIdx.x * 64;
    const int r0 = wn * 16;

    const __bf16* w1base = w1 + (size_t)(wn * 16 + l15) * 192 + q8;
    const __bf16* w2base = w2 + (size_t)(wn * 48 + l15) * 768 + q8;

    f32x4 zero = {0.f, 0.f, 0.f, 0.f};

    // prefetch W1 frags for chunk 0 (in flight during LN)
    bf16x8 w1f[2][6];
    #pragma unroll
    for (int kt = 0; kt < 6; ++kt)
        w1f[0][kt] = *(const bf16x8*)(w1base + kt * 32);

    // per-chunk b1 scalars (h = ch*64 + wn*16 + l15) and b2 scalars
    float bv1s[12];
    #pragma unroll
    for (int ch = 0; ch < 12; ++ch)
        bv1s[ch] = b1[ch * 64 + wn * 16 + l15];
    float bv2s[3];
    #pragma unroll
    for (int tn = 0; tn < 3; ++tn)
        bv2s[tn] = b2[wn * 48 + tn * 16 + l15];

    // ---- fused LN2: wave wn normalizes rows [r0, r0+16) of `out` into As ----
    {
        const float wl0 = n2w[lane], wl1 = n2w[lane + 64], wl2 = n2w[lane + 128];
        const float bl0 = n2b[lane], bl1 = n2b[lane + 64], bl2 = n2b[lane + 128];
        #pragma unroll
        for (int rr = 0; rr < 16; ++rr) {
            const float* xp = out + (size_t)(m0 + r0 + rr) * C_DIM;
            float v0 = xp[lane], v1 = xp[lane + 64], v2 = xp[lane + 128];
            float s = v0 + v1 + v2;
            float sq = v0 * v0 + v1 * v1 + v2 * v2;
            #pragma unroll
            for (int off = 32; off; off >>= 1) {
                s  += __shfl_xor(s, off);
                sq += __shfl_xor(sq, off);
            }
            float mu = s * (1.f / C_DIM);
            float rs = rsqrtf(sq * (1.f / C_DIM) - mu * mu + 1e-5f);
            As[(r0 + rr) * 200 + lane]       = (__bf16)((v0 - mu) * rs * wl0 + bl0);
            As[(r0 + rr) * 200 + lane + 64]  = (__bf16)((v1 - mu) * rs * wl1 + bl1);
            As[(r0 + rr) * 200 + lane + 128] = (__bf16)((v2 - mu) * rs * wl2 + bl2);
        }
    }
    __syncthreads();

    f32x4 acc2[4][3];
    #pragma unroll
    for (int tm = 0; tm < 4; ++tm)
        #pragma unroll
        for (int tn = 0; tn < 3; ++tn) acc2[tm][tn] = zero;

    bf16x8 w2f[6];

    #pragma unroll
    for (int ch = 0; ch < 12; ++ch) {
        const int h0 = ch * 64;
        const int cur = ch & 1, nxt = cur ^ 1;

        // issue next-chunk W1 frags (drain at the mid-chunk barrier, hidden)
        if (ch < 11) {
            #pragma unroll
            for (int kt = 0; kt < 6; ++kt)
                w1f[nxt][kt] = *(const bf16x8*)(w1base + (size_t)(h0 + 64) * 192 + kt * 32);
        }
        // issue this-chunk W2 frags (used after the mid-chunk barrier)
        #pragma unroll
        for (int ks = 0; ks < 2; ++ks)
            #pragma unroll
            for (int tn = 0; tn < 3; ++tn)
                w2f[ks * 3 + tn] = *(const bf16x8*)(w2base + (size_t)(tn * 16) * 768 + h0 + ks * 32);

        // ---- GEMM1: acc1(64x16-per-wave) = As @ W1[h0+wn*16..][:]^T (regs+LDS only)
        f32x4 acc1[4];
        #pragma unroll
        for (int tm = 0; tm < 4; ++tm) acc1[tm] = zero;
        #pragma unroll
        for (int kt = 0; kt < 6; ++kt)
            #pragma unroll
            for (int tm = 0; tm < 4; ++tm) {
                bf16x8 af = *(const bf16x8*)(&As[(tm * 16 + l15) * 200 + kt * 32 + q8]);
                acc1[tm] = __builtin_amdgcn_mfma_f32_16x16x32_bf16(
                    af, w1f[cur][kt], acc1[tm], 0, 0, 0);
            }

        __syncthreads();   // prev-chunk GEMM2 Hs reads done; prefetches drained

        // ---- GELU -> Hs[:, wn*16+l15]
        {
            const float bv = bv1s[ch];
            #pragma unroll
            for (int tm = 0; tm < 4; ++tm)
                #pragma unroll
                for (int r = 0; r < 4; ++r) {
                    int row = tm * 16 + q4 * 4 + r;
                    float v = acc1[tm][r] + bv;
                    float g = v * __builtin_amdgcn_rcpf(1.f + __expf(-1.702f * v));
                    Hs[row * 72 + wn * 16 + l15] = (__bf16)g;
                }
        }
        __syncthreads();   // Hs visible

        // ---- GEMM2: acc2 += Hs(64x64) @ W2[wn*48..][h0..]^T (regs+LDS only)
        #pragma unroll
        for (int ks = 0; ks < 2; ++ks)
            #pragma unroll
            for (int tm = 0; tm < 4; ++tm) {
                bf16x8 ap = *(const bf16x8*)(&Hs[(tm * 16 + l15) * 72 + ks * 32 + q8]);
                #pragma unroll
                for (int tn = 0; tn < 3; ++tn)
                    acc2[tm][tn] = __builtin_amdgcn_mfma_f32_16x16x32_bf16(
                        ap, w2f[ks * 3 + tn], acc2[tm][tn], 0, 0, 0);
            }
    }

    // ---- epilogue: coalesced RMW via LDS transpose (Cs reuses As region) ----
    float* Cs = (float*)As;   // 32 * 196 * 4 = 25088 B <= 25600 B
    #pragma unroll
    for (int pass = 0; pass < 2; ++pass) {
        if (pass) __syncthreads();          // prior read phase done before overwrite
        #pragma unroll
        for (int tmh = 0; tmh < 2; ++tmh) {
            int tm = pass * 2 + tmh;
            #pragma unroll
            for (int tn = 0; tn < 3; ++tn) {
                int c = wn * 48 + tn * 16 + l15;
                float bv = bv2s[tn];
                #pragma unroll
                for (int r = 0; r < 4; ++r) {
                    int rl = tmh * 16 + q4 * 4 + r;
                    Cs[rl * 196 + c] = acc2[tm][tn][r] + bv;
                }
            }
        }
        __syncthreads();
        // coalesced RMW: 32 rows x 192 cols as float4 (48 per row, 1536 total)
        #pragma unroll
        for (int it = 0; it < 6; ++it) {
            int f = it * 256 + tid;
            int row = f / 48, c4 = f - row * 48;
            float4* gp = (float4*)(out + (size_t)(m0 + pass * 32 + row) * C_DIM) + c4;
            float4 g = *gp;
            const float* lp = &Cs[row * 196 + c4 * 4];
            g.x += lp[0]; g.y += lp[1]; g.z += lp[2]; g.w += lp[3];
            *gp = g;
        }
    }
}

// ---------------- MFMA windowed attention: one wave per (window, head) -----------
// SWAPPED QK^T + wave-private LDS + no block barrier (R6, measured good).
__global__ __launch_bounds__(256, 2)
void attn_mfma_kernel(const __bf16* __restrict__ qkv,
                      const float* __restrict__ bias_g,
                      __bf16* __restrict__ out)
{
    const int wave = threadIdx.x >> 6;
    const int lane = threadIdx.x & 63;
    const int pair = blockIdx.x * 4 + wave;       // 12288 pairs
    const int w = pair / 6, head = pair - (pair / 6) * 6;

    __shared__ __bf16 vsT_s[4][32 * 72];          // V^T: [d][j], stride 72
    __shared__ __bf16 Ps_s[4][64 * 72];           // P:   [i][j], stride 72
    __bf16* vsT = vsT_s[wave];
    __bf16* Ps  = Ps_s[wave];

    const int l15 = lane & 15, q4 = lane >> 4, q8 = q4 << 3;
    const size_t qbase = (size_t)w * 49 * 576 + head * 32;

    // stage V transposed: vsT[d][j] = V[j][d]; zero k-padding j in [49,64)
    {
        int d = lane & 31, jh = lane >> 5;
        #pragma unroll
        for (int it = 0; it < 25; ++it) {
            int j = it * 2 + jh;
            if (j < 49)
                vsT[d * 72 + j] = qkv[qbase + (size_t)j * 576 + 384 + d];
        }
        for (int idx = lane; idx < 32 * 15; idx += 64) {
            int dd = idx / 15, jj = 49 + (idx - dd * 15);
            vsT[dd * 72 + jj] = (__bf16)0.f;
        }
    }

    bf16x8 qf[4], kf[4];
    #pragma unroll
    for (int t = 0; t < 4; ++t) {
        int row = t * 16 + l15;
        int rq = row < 49 ? row : 48;
        qf[t] = *(const bf16x8*)(qkv + qbase + (size_t)rq * 576 + q8);
        kf[t] = *(const bf16x8*)(qkv + qbase + (size_t)rq * 576 + 192 + q8);
    }

    // ---- QK^T, swapped operands: sc[tn][tm][r] = S[i=tm*16+l15][j=tn*16+q4*4+r]
    f32x4 sc[4][4];
    f32x4 zero = {0.f, 0.f, 0.f, 0.f};
    #pragma unroll
    for (int tn = 0; tn < 4; ++tn)
        #pragma unroll
        for (int tm = 0; tm < 4; ++tm) sc[tn][tm] = zero;
    __builtin_amdgcn_s_setprio(1);
    #pragma unroll
    for (int tn = 0; tn < 4; ++tn)
        #pragma unroll
        for (int tm = 0; tm < 4; ++tm)
            sc[tn][tm] = __builtin_amdgcn_mfma_f32_16x16x32_bf16(
                kf[tn], qf[tm], sc[tn][tm], 0, 0, 0);
    __builtin_amdgcn_s_setprio(0);

    const float scale = 0.17677669529663687f;      // 1/sqrt(32)
    const int hbase = head * 2401;
    const int jb4 = q4 * 4;
    #pragma unroll
    for (int tm = 0; tm < 4; ++tm) {
        int i = tm * 16 + l15;
        int ioff = hbase + (i < 49 ? i : 48) * 49;
        float v[4][4];
        #pragma unroll
        for (int tn = 0; tn < 4; ++tn) {
            int jb = tn * 16 + jb4;
            #pragma unroll
            for (int r = 0; r < 4; ++r) {
                int j = jb + r;
                float bz = (j < 49) ? bias_g[ioff + j] : 0.f;
                float t = sc[tn][tm][r] * scale + bz;
                v[tn][r] = (j < 49) ? t : -1e30f;
            }
        }
        // row max: 15 local + 2 cross-group shuffles
        float mx = v[0][0];
        #pragma unroll
        for (int tn = 0; tn < 4; ++tn)
            #pragma unroll
            for (int r = 0; r < 4; ++r) mx = fmaxf(mx, v[tn][r]);
        mx = fmaxf(mx, __shfl_xor(mx, 16));
        mx = fmaxf(mx, __shfl_xor(mx, 32));
        float sm = 0.f;
        #pragma unroll
        for (int tn = 0; tn < 4; ++tn)
            #pragma unroll
            for (int r = 0; r < 4; ++r) {
                float e = __expf(v[tn][r] - mx);
                v[tn][r] = e;
                sm += e;
            }
        sm += __shfl_xor(sm, 16);
        sm += __shfl_xor(sm, 32);
        float inv = __builtin_amdgcn_rcpf(sm);
        if (i < 49) {
            #pragma unroll
            for (int tn = 0; tn < 4; ++tn) {
                int jb = tn * 16 + jb4;
                bf16x4 pk;
                #pragma unroll
                for (int r = 0; r < 4; ++r)
                    pk[r] = (__bf16)((jb + r < 49) ? v[tn][r] * inv : 0.f);
                *(bf16x4*)(&Ps[i * 72 + jb]) = pk;
            }
        }
    }

    // no __syncthreads: vsT/Ps wave-private, DS in-order within a wave

    f32x4 oc[4][2];
    #pragma unroll
    for (int tm = 0; tm < 4; ++tm)
        #pragma unroll
        for (int tn = 0; tn < 2; ++tn) oc[tm][tn] = zero;
    #pragma unroll
    for (int ks = 0; ks < 2; ++ks) {
        bf16x8 bv[2];
        #pragma unroll
        for (int tn = 0; tn < 2; ++tn)
            bv[tn] = *(const bf16x8*)(vsT + (tn * 16 + l15) * 72 + ks * 32 + q8);
        __builtin_amdgcn_s_setprio(1);
        #pragma unroll
        for (int tm = 0; tm < 4; ++tm) {
            bf16x8 ap = *(const bf16x8*)(Ps + (tm * 16 + l15) * 72 + ks * 32 + q8);
            #pragma unroll
            for (int tn = 0; tn < 2; ++tn)
                oc[tm][tn] = __builtin_amdgcn_mfma_f32_16x16x32_bf16(
                    ap, bv[tn], oc[tm][tn], 0, 0, 0);
        }
        __builtin_amdgcn_s_setprio(0);
    }

    #pragma unroll
    for (int tm = 0; tm < 4; ++tm) {
        #pragma unroll
        for (int r = 0; r < 4; ++r) {
            int m = tm * 16 + q4 * 4 + r;
            if (m < 49) {
                __bf16* op = out + (size_t)(w * 49 + m) * C_DIM + head * 32;
                #pragma unroll
                for (int tn = 0; tn < 2; ++tn)
                    op[tn * 16 + l15] = (__bf16)(oc[tm][tn][r]);
            }
        }
    }
}

extern "C" void kernel_launch(void* const* d_in, const int* in_sizes, int n_in,
                              void* d_out, int out_size, void* d_ws, size_t ws_size,
                              hipStream_t stream) {
    const float* x     = (const float*)d_in[0];
    const float* n1w   = (const float*)d_in[1];
    const float* n1b   = (const float*)d_in[2];
    const float* qkvw  = (const float*)d_in[3];
    const float* qkvb  = (const float*)d_in[4];
    const float* rpb   = (const float*)d_in[5];
    const float* projw = (const float*)d_in[6];
    const float* projb = (const float*)d_in[7];
    const float* n2w   = (const float*)d_in[8];
    const float* n2b   = (const float*)d_in[9];
    const float* fc1w  = (const float*)d_in[10];
    const float* fc1b  = (const float*)d_in[11];
    const float* fc2w  = (const float*)d_in[12];
    const float* fc2b  = (const float*)d_in[13];
    float* out = (float*)d_out;
    char* ws = (char*)d_ws;

    // ws layout — ALL regions disjoint, no lifetime aliasing:
    //   bufA    @ 0           : 100352*192 bf16 = 38,535,168
    //   bufQ    @ 38,535,168  : 100352*576 bf16 = 115,605,504 -> ends 154,140,672
    //   qkvw_b  @ 154,140,672 : 221,184
    //   projw_b @ 154,361,856 : 73,728
    //   fc1w_b  @ 154,435,584 : 294,912
    //   fc2w_b  @ 154,730,496 : 294,912
    //   bias_g  @ 155,025,408 : 57,624   -> ends 155,083,032
    __bf16* bufA    = (__bf16*)ws;
    __bf16* bufQ    = (__bf16*)(ws + 38535168);
    __bf16* qkvw_b  = (__bf16*)(ws + 154140672);
    __bf16* projw_b = (__bf16*)(ws + 154361856);
    __bf16* fc1w_b  = (__bf16*)(ws + 154435584);
    __bf16* fc2w_b  = (__bf16*)(ws + 154730496);
    float*  bias_g  = (float*) (ws + 155025408);

    // 0. weight conversions + bias expansion (tiny)
    cvt_kernel<<<(110592/8 + 255)/256, 256, 0, stream>>>(qkvw, qkvw_b, 110592/8);
    cvt_kernel<<<(36864/8  + 255)/256, 256, 0, stream>>>(projw, projw_b, 36864/8);
    cvt_kernel<<<(147456/8 + 255)/256, 256, 0, stream>>>(fc1w, fc1w_b, 147456/8);
    cvt_kernel<<<(147456/8 + 255)/256, 256, 0, stream>>>(fc2w, fc2w_b, 147456/8);
    bias_expand_kernel<<<(NHEADS*2401 + 255)/256, 256, 0, stream>>>(rpb, bias_g);

    // 1+2. fused LN1 + shift/window-partition + QKV GEMM -> bufQ
    qkv_ln_kernel<<<NTOK / 128, 256, 0, stream>>>(
        x, n1w, n1b, qkvw_b, qkvb, bufQ);
    // 3. windowed attention (MFMA, swapped-QK^T softmax)
    attn_mfma_kernel<<<NWIN * NHEADS / 4, 256, 0, stream>>>(bufQ, bias_g, bufA);
    // 4. proj GEMM + window reverse + residual -> d_out
    gemm_kernel<1><<<dim3(3, NTOK / 128), 256, 0, stream>>>(
        bufA, projw_b, projb, (void*)out, x, 192, 192);
    // 5+6+7. fused LN2 + MLP (FC1 + GELU + FC2 + residual), R4 structure
    mlp_fused_kernel<<<NTOK / 64, 256, 0, stream>>>(
        n2w, n2b, fc1w_b, fc1b, fc2w_b, fc2b, out);
}

// Round 8
// 463.510 us; speedup vs baseline: 1.1388x; 1.1388x over previous
//
#include <hip/hip_runtime.h>
#include <hip/hip_bf16.h>
#include <cmath>

typedef float f32x4 __attribute__((ext_vector_type(4)));
typedef __bf16 bf16x8 __attribute__((ext_vector_type(8)));
typedef __bf16 bf16x4 __attribute__((ext_vector_type(4)));

#define WS_SZ 7
#define SHIFT 3
#define HGRID 56
#define C_DIM 192
#define NHEADS 6
#define HDIM 32
#define NTOK 100352   // 32 * 3136
#define NWIN 2048     // 32 * 8 * 8

// map window-space row (w*49+i) -> original token index (inverse roll by +SHIFT)
__device__ __forceinline__ int win_to_tok(int wrow) {
    int w = wrow / 49, i = wrow - w * 49;
    int b = w >> 6, rem = w & 63;
    int wy = rem >> 3, wx = rem & 7;
    int yi = i / 7, xi = i - yi * 7;
    int y = wy * 7 + yi + SHIFT; if (y >= HGRID) y -= HGRID;
    int x = wx * 7 + xi + SHIFT; if (x >= HGRID) x -= HGRID;
    return b * (HGRID * HGRID) + y * HGRID + x;
}

// ---------------- fp32 -> bf16 weight conversion (8 elems/thread) ----------------
__global__ __launch_bounds__(256)
void cvt_kernel(const float* __restrict__ src, __bf16* __restrict__ dst, int n8)
{
    int idx = blockIdx.x * 256 + threadIdx.x;
    if (idx >= n8) return;
    float4 a = ((const float4*)src)[idx * 2];
    float4 b = ((const float4*)src)[idx * 2 + 1];
    bf16x8 o;
    o[0] = (__bf16)a.x; o[1] = (__bf16)a.y; o[2] = (__bf16)a.z; o[3] = (__bf16)a.w;
    o[4] = (__bf16)b.x; o[5] = (__bf16)b.y; o[6] = (__bf16)b.z; o[7] = (__bf16)b.w;
    ((bf16x8*)dst)[idx] = o;
}

// ---------------- expand rel-pos bias -> bias_g[head][49][49] fp32 ----------------
__global__ __launch_bounds__(256)
void bias_expand_kernel(const float* __restrict__ rpb, float* __restrict__ bias_g)
{
    int idx = blockIdx.x * 256 + threadIdx.x;
    if (idx >= NHEADS * 2401) return;
    int h = idx / 2401, rem = idx - h * 2401;
    int i = rem / 49, j = rem - i * 49;
    int yi = i / 7, xi = i - yi * 7;
    int yj = j / 7, xj = j - yj * 7;
    int ri = (yi - yj + 6) * 13 + (xi - xj + 6);
    bias_g[idx] = rpb[ri * NHEADS + h];
}

// ---------------- LayerNorm (one wave per token) ----------------
template<int WINDOWED>
__global__ __launch_bounds__(256)
void ln_kernel(const float* __restrict__ x, const float* __restrict__ w,
               const float* __restrict__ b, __bf16* __restrict__ out)
{
    int r = blockIdx.x * 4 + (threadIdx.x >> 6);
    int lane = threadIdx.x & 63;
    int src = WINDOWED ? win_to_tok(r) : r;
    const float* xp = x + (size_t)src * C_DIM;
    float v0 = xp[lane], v1 = xp[lane + 64], v2 = xp[lane + 128];
    float s = v0 + v1 + v2;
    float sq = v0 * v0 + v1 * v1 + v2 * v2;
    #pragma unroll
    for (int off = 32; off; off >>= 1) {
        s  += __shfl_xor(s, off);
        sq += __shfl_xor(sq, off);
    }
    float mu = s * (1.f / C_DIM);
    float rs = rsqrtf(sq * (1.f / C_DIM) - mu * mu + 1e-5f);
    __bf16* op = out + (size_t)r * C_DIM;
    op[lane]       = (__bf16)((v0 - mu) * rs * w[lane]       + b[lane]);
    op[lane + 64]  = (__bf16)((v1 - mu) * rs * w[lane + 64]  + b[lane + 64]);
    op[lane + 128] = (__bf16)((v2 - mu) * rs * w[lane + 128] + b[lane + 128]);
}

// ---------------- GEMM: out = A(bf16, MxK) @ W(bf16, NxK)^T + bias ----------------
// Grid: x = n-tile (fast -> consecutive blocks share the A tile in L2), y = m-tile.
// MODE 0: store bf16. MODE 1: window-reverse scatter + residual -> fp32.
template<int MODE>
__global__ __launch_bounds__(256)
void gemm_kernel(const __bf16* __restrict__ A, const __bf16* __restrict__ W,
                 const float* __restrict__ bias, void* __restrict__ outp,
                 const float* __restrict__ resid, int N, int K)
{
    __shared__ __bf16 As[128 * 40];
    __shared__ __bf16 Bs[64 * 40];
    const int tid = threadIdx.x;
    const int wave = tid >> 6, lane = tid & 63;
    const int wm = wave >> 1, wn = wave & 1;
    const int l15 = lane & 15, q8 = (lane >> 4) << 3;
    const int m0 = blockIdx.y * 128, n0 = blockIdx.x * 64;

    f32x4 acc[4][2];
    f32x4 zero = {0.f, 0.f, 0.f, 0.f};
    #pragma unroll
    for (int i = 0; i < 4; i++)
        #pragma unroll
        for (int j = 0; j < 2; j++) acc[i][j] = zero;

    const int br = tid >> 2, bc = (tid & 3) << 3;
    for (int kt = 0; kt < K; kt += 32) {
        __syncthreads();
        #pragma unroll
        for (int it = 0; it < 2; it++) {
            int idx = it * 256 + tid;
            int r = idx >> 2, c = (idx & 3) << 3;
            *(uint4*)(&As[r * 40 + c]) =
                *(const uint4*)(A + (size_t)(m0 + r) * K + kt + c);
        }
        *(uint4*)(&Bs[br * 40 + bc]) =
            *(const uint4*)(W + (size_t)(n0 + br) * K + kt + bc);
        __syncthreads();
        bf16x8 af[4], bfr[2];
        #pragma unroll
        for (int fm = 0; fm < 4; fm++)
            af[fm] = *(const bf16x8*)(&As[(wm * 64 + fm * 16 + l15) * 40 + q8]);
        #pragma unroll
        for (int fn = 0; fn < 2; fn++)
            bfr[fn] = *(const bf16x8*)(&Bs[(wn * 32 + fn * 16 + l15) * 40 + q8]);
        #pragma unroll
        for (int fm = 0; fm < 4; fm++)
            #pragma unroll
            for (int fn = 0; fn < 2; fn++)
                acc[fm][fn] = __builtin_amdgcn_mfma_f32_16x16x32_bf16(
                    af[fm], bfr[fn], acc[fm][fn], 0, 0, 0);
    }

    const int l4 = lane >> 4;
    #pragma unroll
    for (int fm = 0; fm < 4; fm++) {
        #pragma unroll
        for (int fn = 0; fn < 2; fn++) {
            int c = n0 + wn * 32 + fn * 16 + l15;
            float bv = bias[c];
            #pragma unroll
            for (int r = 0; r < 4; r++) {
                int m = m0 + wm * 64 + fm * 16 + l4 * 4 + r;
                float v = acc[fm][fn][r] + bv;
                if (MODE == 0) {
                    ((__bf16*)outp)[(size_t)m * N + c] = (__bf16)v;
                } else {
                    int t = win_to_tok(m);
                    ((float*)outp)[(size_t)t * C_DIM + c] =
                        resid[(size_t)t * C_DIM + c] + v;
                }
            }
        }
    }
}

// ---------------- Fused LN2 + MLP (exact R4 structure, best measured: 159us) ----
__global__ __launch_bounds__(256, 3)
void mlp_fused_kernel(const float* __restrict__ n2w, const float* __restrict__ n2b,
                      const __bf16* __restrict__ w1,  // 768 x 192
                      const float* __restrict__ b1,
                      const __bf16* __restrict__ w2,  // 192 x 768
                      const float* __restrict__ b2,
                      float* __restrict__ out)        // NTOK x 192 fp32, RMW
{
    __shared__ __align__(16) __bf16 As[64 * 200]; // 25600B; reused as fp32 Cs[32][196]
    __shared__ __bf16 Hs[64 * 72];                // 9216B, stride 144B: 2-way banks
    const int tid = threadIdx.x;
    const int wn = tid >> 6, lane = tid & 63;
    const int l15 = lane & 15, q4 = lane >> 4, q8 = q4 << 3;
    const int m0 = blockIdx.x * 64;
    const int r0 = wn * 16;

    const __bf16* w1base = w1 + (size_t)(wn * 16 + l15) * 192 + q8;
    const __bf16* w2base = w2 + (size_t)(wn * 48 + l15) * 768 + q8;

    f32x4 zero = {0.f, 0.f, 0.f, 0.f};

    // prefetch W1 frags for chunk 0 (in flight during LN)
    bf16x8 w1f[2][6];
    #pragma unroll
    for (int kt = 0; kt < 6; ++kt)
        w1f[0][kt] = *(const bf16x8*)(w1base + kt * 32);

    // per-chunk b1 scalars (h = ch*64 + wn*16 + l15) and b2 scalars
    float bv1s[12];
    #pragma unroll
    for (int ch = 0; ch < 12; ++ch)
        bv1s[ch] = b1[ch * 64 + wn * 16 + l15];
    float bv2s[3];
    #pragma unroll
    for (int tn = 0; tn < 3; ++tn)
        bv2s[tn] = b2[wn * 48 + tn * 16 + l15];

    // ---- fused LN2: wave wn normalizes rows [r0, r0+16) of `out` into As ----
    {
        const float wl0 = n2w[lane], wl1 = n2w[lane + 64], wl2 = n2w[lane + 128];
        const float bl0 = n2b[lane], bl1 = n2b[lane + 64], bl2 = n2b[lane + 128];
        #pragma unroll
        for (int rr = 0; rr < 16; ++rr) {
            const float* xp = out + (size_t)(m0 + r0 + rr) * C_DIM;
            float v0 = xp[lane], v1 = xp[lane + 64], v2 = xp[lane + 128];
            float s = v0 + v1 + v2;
            float sq = v0 * v0 + v1 * v1 + v2 * v2;
            #pragma unroll
            for (int off = 32; off; off >>= 1) {
                s  += __shfl_xor(s, off);
                sq += __shfl_xor(sq, off);
            }
            float mu = s * (1.f / C_DIM);
            float rs = rsqrtf(sq * (1.f / C_DIM) - mu * mu + 1e-5f);
            As[(r0 + rr) * 200 + lane]       = (__bf16)((v0 - mu) * rs * wl0 + bl0);
            As[(r0 + rr) * 200 + lane + 64]  = (__bf16)((v1 - mu) * rs * wl1 + bl1);
            As[(r0 + rr) * 200 + lane + 128] = (__bf16)((v2 - mu) * rs * wl2 + bl2);
        }
    }
    __syncthreads();

    f32x4 acc2[4][3];
    #pragma unroll
    for (int tm = 0; tm < 4; ++tm)
        #pragma unroll
        for (int tn = 0; tn < 3; ++tn) acc2[tm][tn] = zero;

    bf16x8 w2f[6];

    #pragma unroll
    for (int ch = 0; ch < 12; ++ch) {
        const int h0 = ch * 64;
        const int cur = ch & 1, nxt = cur ^ 1;

        // issue next-chunk W1 frags (drain at the mid-chunk barrier, hidden)
        if (ch < 11) {
            #pragma unroll
            for (int kt = 0; kt < 6; ++kt)
                w1f[nxt][kt] = *(const bf16x8*)(w1base + (size_t)(h0 + 64) * 192 + kt * 32);
        }
        // issue this-chunk W2 frags (used after the mid-chunk barrier)
        #pragma unroll
        for (int ks = 0; ks < 2; ++ks)
            #pragma unroll
            for (int tn = 0; tn < 3; ++tn)
                w2f[ks * 3 + tn] = *(const bf16x8*)(w2base + (size_t)(tn * 16) * 768 + h0 + ks * 32);

        // ---- GEMM1: acc1(64x16-per-wave) = As @ W1[h0+wn*16..][:]^T (regs+LDS only)
        f32x4 acc1[4];
        #pragma unroll
        for (int tm = 0; tm < 4; ++tm) acc1[tm] = zero;
        #pragma unroll
        for (int kt = 0; kt < 6; ++kt)
            #pragma unroll
            for (int tm = 0; tm < 4; ++tm) {
                bf16x8 af = *(const bf16x8*)(&As[(tm * 16 + l15) * 200 + kt * 32 + q8]);
                acc1[tm] = __builtin_amdgcn_mfma_f32_16x16x32_bf16(
                    af, w1f[cur][kt], acc1[tm], 0, 0, 0);
            }

        __syncthreads();   // prev-chunk GEMM2 Hs reads done; prefetches drained

        // ---- GELU -> Hs[:, wn*16+l15]
        {
            const float bv = bv1s[ch];
            #pragma unroll
            for (int tm = 0; tm < 4; ++tm)
                #pragma unroll
                for (int r = 0; r < 4; ++r) {
                    int row = tm * 16 + q4 * 4 + r;
                    float v = acc1[tm][r] + bv;
                    float g = v * __builtin_amdgcn_rcpf(1.f + __expf(-1.702f * v));
                    Hs[row * 72 + wn * 16 + l15] = (__bf16)g;
                }
        }
        __syncthreads();   // Hs visible

        // ---- GEMM2: acc2 += Hs(64x64) @ W2[wn*48..][h0..]^T (regs+LDS only)
        #pragma unroll
        for (int ks = 0; ks < 2; ++ks)
            #pragma unroll
            for (int tm = 0; tm < 4; ++tm) {
                bf16x8 ap = *(const bf16x8*)(&Hs[(tm * 16 + l15) * 72 + ks * 32 + q8]);
                #pragma unroll
                for (int tn = 0; tn < 3; ++tn)
                    acc2[tm][tn] = __builtin_amdgcn_mfma_f32_16x16x32_bf16(
                        ap, w2f[ks * 3 + tn], acc2[tm][tn], 0, 0, 0);
            }
    }

    // ---- epilogue: coalesced RMW via LDS transpose (Cs reuses As region) ----
    float* Cs = (float*)As;   // 32 * 196 * 4 = 25088 B <= 25600 B
    #pragma unroll
    for (int pass = 0; pass < 2; ++pass) {
        if (pass) __syncthreads();          // prior read phase done before overwrite
        #pragma unroll
        for (int tmh = 0; tmh < 2; ++tmh) {
            int tm = pass * 2 + tmh;
            #pragma unroll
            for (int tn = 0; tn < 3; ++tn) {
                int c = wn * 48 + tn * 16 + l15;
                float bv = bv2s[tn];
                #pragma unroll
                for (int r = 0; r < 4; ++r) {
                    int rl = tmh * 16 + q4 * 4 + r;
                    Cs[rl * 196 + c] = acc2[tm][tn][r] + bv;
                }
            }
        }
        __syncthreads();
        // coalesced RMW: 32 rows x 192 cols as float4 (48 per row, 1536 total)
        #pragma unroll
        for (int it = 0; it < 6; ++it) {
            int f = it * 256 + tid;
            int row = f / 48, c4 = f - row * 48;
            float4* gp = (float4*)(out + (size_t)(m0 + pass * 32 + row) * C_DIM) + c4;
            float4 g = *gp;
            const float* lp = &Cs[row * 196 + c4 * 4];
            g.x += lp[0]; g.y += lp[1]; g.z += lp[2]; g.w += lp[3];
            *gp = g;
        }
    }
}

// ---------------- MFMA windowed attention: ONE WAVE PER BLOCK --------------------
// 64 threads, 13.8KB LDS -> ~11 blocks/CU (was 8 waves/CU at 4-wave/55KB blocks).
// Q/K frag loads issued FIRST (they gate QK^T); V staging vectorized:
// 4 x 16B loads + 32 scalar ds_writes (was 50 scalar loads + 50 scalar writes).
// Swapped QK^T softmax (R6). vsT/Ps wave-private; no barriers at all.
__global__ __launch_bounds__(64)
void attn_mfma_kernel(const __bf16* __restrict__ qkv,
                      const float* __restrict__ bias_g,
                      __bf16* __restrict__ out)
{
    const int lane = threadIdx.x & 63;
    const int pair = blockIdx.x;                  // 12288 pairs
    const int w = pair / 6, head = pair - (pair / 6) * 6;

    __shared__ __bf16 vsT[32 * 72];               // V^T: [d][j], stride 72
    __shared__ __bf16 Ps[64 * 72];                // P:   [i][j], stride 72

    const int l15 = lane & 15, q4 = lane >> 4, q8 = q4 << 3;
    const size_t qbase = (size_t)w * 49 * 576 + head * 32;

    // ---- Q/K frags first: these gate the QK^T MFMAs ----
    bf16x8 qf[4], kf[4];
    #pragma unroll
    for (int t = 0; t < 4; ++t) {
        int row = t * 16 + l15;
        int rq = row < 49 ? row : 48;
        qf[t] = *(const bf16x8*)(qkv + qbase + (size_t)rq * 576 + q8);
        kf[t] = *(const bf16x8*)(qkv + qbase + (size_t)rq * 576 + 192 + q8);
    }

    // ---- stage V transposed (vectorized): lane covers (j = p*16 + lane>>2,
    //      d = (lane&3)*8 .. +8). vsT[d][j] = V[j][d]; zero pad j in [49,64).
    {
        int j0 = lane >> 2, dq = (lane & 3) << 3;
        #pragma unroll
        for (int p = 0; p < 4; ++p) {
            int j = p * 16 + j0;
            if (j < 49) {
                bf16x8 vv = *(const bf16x8*)(qkv + qbase + (size_t)j * 576 + 384 + dq);
                #pragma unroll
                for (int e = 0; e < 8; ++e)
                    vsT[(dq + e) * 72 + j] = vv[e];
            }
        }
        for (int idx = lane; idx < 32 * 15; idx += 64) {
            int dd = idx / 15, jj = 49 + (idx - dd * 15);
            vsT[dd * 72 + jj] = (__bf16)0.f;
        }
    }

    // ---- QK^T, swapped operands: sc[tn][tm][r] = S[i=tm*16+l15][j=tn*16+q4*4+r]
    f32x4 sc[4][4];
    f32x4 zero = {0.f, 0.f, 0.f, 0.f};
    #pragma unroll
    for (int tn = 0; tn < 4; ++tn)
        #pragma unroll
        for (int tm = 0; tm < 4; ++tm) sc[tn][tm] = zero;
    __builtin_amdgcn_s_setprio(1);
    #pragma unroll
    for (int tn = 0; tn < 4; ++tn)
        #pragma unroll
        for (int tm = 0; tm < 4; ++tm)
            sc[tn][tm] = __builtin_amdgcn_mfma_f32_16x16x32_bf16(
                kf[tn], qf[tm], sc[tn][tm], 0, 0, 0);
    __builtin_amdgcn_s_setprio(0);

    const float scale = 0.17677669529663687f;      // 1/sqrt(32)
    const int hbase = head * 2401;
    const int jb4 = q4 * 4;
    #pragma unroll
    for (int tm = 0; tm < 4; ++tm) {
        int i = tm * 16 + l15;
        int ioff = hbase + (i < 49 ? i : 48) * 49;
        float v[4][4];
        #pragma unroll
        for (int tn = 0; tn < 4; ++tn) {
            int jb = tn * 16 + jb4;
            #pragma unroll
            for (int r = 0; r < 4; ++r) {
                int j = jb + r;
                float bz = (j < 49) ? bias_g[ioff + j] : 0.f;
                float t = sc[tn][tm][r] * scale + bz;
                v[tn][r] = (j < 49) ? t : -1e30f;
            }
        }
        // row max: 15 local + 2 cross-group shuffles
        float mx = v[0][0];
        #pragma unroll
        for (int tn = 0; tn < 4; ++tn)
            #pragma unroll
            for (int r = 0; r < 4; ++r) mx = fmaxf(mx, v[tn][r]);
        mx = fmaxf(mx, __shfl_xor(mx, 16));
        mx = fmaxf(mx, __shfl_xor(mx, 32));
        float sm = 0.f;
        #pragma unroll
        for (int tn = 0; tn < 4; ++tn)
            #pragma unroll
            for (int r = 0; r < 4; ++r) {
                float e = __expf(v[tn][r] - mx);
                v[tn][r] = e;
                sm += e;
            }
        sm += __shfl_xor(sm, 16);
        sm += __shfl_xor(sm, 32);
        float inv = __builtin_amdgcn_rcpf(sm);
        if (i < 49) {
            #pragma unroll
            for (int tn = 0; tn < 4; ++tn) {
                int jb = tn * 16 + jb4;
                bf16x4 pk;
                #pragma unroll
                for (int r = 0; r < 4; ++r)
                    pk[r] = (__bf16)((jb + r < 49) ? v[tn][r] * inv : 0.f);
                *(bf16x4*)(&Ps[i * 72 + jb]) = pk;
            }
        }
    }

    // no barriers: vsT/Ps wave-private, DS in-order within a wave

    f32x4 oc[4][2];
    #pragma unroll
    for (int tm = 0; tm < 4; ++tm)
        #pragma unroll
        for (int tn = 0; tn < 2; ++tn) oc[tm][tn] = zero;
    #pragma unroll
    for (int ks = 0; ks < 2; ++ks) {
        bf16x8 bv[2];
        #pragma unroll
        for (int tn = 0; tn < 2; ++tn)
            bv[tn] = *(const bf16x8*)(vsT + (tn * 16 + l15) * 72 + ks * 32 + q8);
        __builtin_amdgcn_s_setprio(1);
        #pragma unroll
        for (int tm = 0; tm < 4; ++tm) {
            bf16x8 ap = *(const bf16x8*)(Ps + (tm * 16 + l15) * 72 + ks * 32 + q8);
            #pragma unroll
            for (int tn = 0; tn < 2; ++tn)
                oc[tm][tn] = __builtin_amdgcn_mfma_f32_16x16x32_bf16(
                    ap, bv[tn], oc[tm][tn], 0, 0, 0);
        }
        __builtin_amdgcn_s_setprio(0);
    }

    #pragma unroll
    for (int tm = 0; tm < 4; ++tm) {
        #pragma unroll
        for (int r = 0; r < 4; ++r) {
            int m = tm * 16 + q4 * 4 + r;
            if (m < 49) {
                __bf16* op = out + (size_t)(w * 49 + m) * C_DIM + head * 32;
                #pragma unroll
                for (int tn = 0; tn < 2; ++tn)
                    op[tn * 16 + l15] = (__bf16)(oc[tm][tn][r]);
            }
        }
    }
}

extern "C" void kernel_launch(void* const* d_in, const int* in_sizes, int n_in,
                              void* d_out, int out_size, void* d_ws, size_t ws_size,
                              hipStream_t stream) {
    const float* x     = (const float*)d_in[0];
    const float* n1w   = (const float*)d_in[1];
    const float* n1b   = (const float*)d_in[2];
    const float* qkvw  = (const float*)d_in[3];
    const float* qkvb  = (const float*)d_in[4];
    const float* rpb   = (const float*)d_in[5];
    const float* projw = (const float*)d_in[6];
    const float* projb = (const float*)d_in[7];
    const float* n2w   = (const float*)d_in[8];
    const float* n2b   = (const float*)d_in[9];
    const float* fc1w  = (const float*)d_in[10];
    const float* fc1b  = (const float*)d_in[11];
    const float* fc2w  = (const float*)d_in[12];
    const float* fc2b  = (const float*)d_in[13];
    float* out = (float*)d_out;
    char* ws = (char*)d_ws;

    // ws layout — ALL regions disjoint, no lifetime aliasing:
    //   bufA    @ 0           : 100352*192 bf16 = 38,535,168
    //   bufQ    @ 38,535,168  : 100352*576 bf16 = 115,605,504 -> ends 154,140,672
    //   qkvw_b  @ 154,140,672 : 221,184
    //   projw_b @ 154,361,856 : 73,728
    //   fc1w_b  @ 154,435,584 : 294,912
    //   fc2w_b  @ 154,730,496 : 294,912
    //   bias_g  @ 155,025,408 : 57,624   -> ends 155,083,032
    __bf16* bufA    = (__bf16*)ws;
    __bf16* bufQ    = (__bf16*)(ws + 38535168);
    __bf16* qkvw_b  = (__bf16*)(ws + 154140672);
    __bf16* projw_b = (__bf16*)(ws + 154361856);
    __bf16* fc1w_b  = (__bf16*)(ws + 154435584);
    __bf16* fc2w_b  = (__bf16*)(ws + 154730496);
    float*  bias_g  = (float*) (ws + 155025408);

    // 0. weight conversions + bias expansion (tiny)
    cvt_kernel<<<(110592/8 + 255)/256, 256, 0, stream>>>(qkvw, qkvw_b, 110592/8);
    cvt_kernel<<<(36864/8  + 255)/256, 256, 0, stream>>>(projw, projw_b, 36864/8);
    cvt_kernel<<<(147456/8 + 255)/256, 256, 0, stream>>>(fc1w, fc1w_b, 147456/8);
    cvt_kernel<<<(147456/8 + 255)/256, 256, 0, stream>>>(fc2w, fc2w_b, 147456/8);
    bias_expand_kernel<<<(NHEADS*2401 + 255)/256, 256, 0, stream>>>(rpb, bias_g);

    // 1. LN1 + shift + window partition
    ln_kernel<1><<<NTOK / 4, 256, 0, stream>>>(x, n1w, n1b, bufA);
    // 2. QKV GEMM (n-fast grid for A-tile L2 reuse)
    gemm_kernel<0><<<dim3(9, NTOK / 128), 256, 0, stream>>>(
        bufA, qkvw_b, qkvb, bufQ, nullptr, 576, 192);
    // 3. windowed attention (MFMA, 1 wave/block, swapped-QK^T softmax)
    attn_mfma_kernel<<<NWIN * NHEADS, 64, 0, stream>>>(bufQ, bias_g, bufA);
    // 4. proj GEMM + window reverse + residual -> d_out
    gemm_kernel<1><<<dim3(3, NTOK / 128), 256, 0, stream>>>(
        bufA, projw_b, projb, (void*)out, x, 192, 192);
    // 5+6+7. fused LN2 + MLP (FC1 + GELU + FC2 + residual), R4 structure
    mlp_fused_kernel<<<NTOK / 64, 256, 0, stream>>>(
        n2w, n2b, fc1w_b, fc1b, fc2w_b, fc2b, out);
}